// Round 10
// baseline (86.155 us; speedup 1.0000x reference)
//
#include <hip/hip_runtime.h>

#define NELEM 21600
#define KSEL 1000
#define MAXB 18
#define NT 1024
#define CAP 2048
#define NCHUNK 8
#define QC 4050                     // float4s per K1 block (32400/8)
#define NFULL 21                    // 21*1024 = 21504
#define NTAIL (NELEM - NFULL * NT)  // 96

typedef unsigned long long ull;

// monotone map: ascending uint key <-> ascending float
__device__ __forceinline__ unsigned fkey(float f) {
  unsigned u = __float_as_uint(f);
  return (u & 0x80000000u) ? ~u : (u | 0x80000000u);
}
__device__ __forceinline__ float unfkey(unsigned k) {
  unsigned u = (k & 0x80000000u) ? (k ^ 0x80000000u) : ~k;
  return __uint_as_float(u);
}

#define K1PROC(v, g) { int r = (g) % 3; \
  if (r == 0) { unsigned key = fkey((v).x); gk[2 * ((g) / 3)] = key; atomicAdd(&h[key >> 21], 1u); } \
  else if (r == 1) { unsigned key = fkey((v).z); gk[2 * ((g) / 3) + 1] = key; atomicAdd(&h[key >> 21], 1u); } }

// ---------------- K1: full-chip float4-coalesced scan -> keys + chunk hists ----
__global__ __launch_bounds__(NT) void k1_scan(
    const float* __restrict__ x, unsigned* __restrict__ gkeys,
    unsigned* __restrict__ ghist) {
  const int blk = blockIdx.x;
  const int s = blk / NCHUNK, c = blk % NCHUNK;
  const int t = threadIdx.x;
  const float4* xq = (const float4*)(x + (size_t)s * NELEM * 6);
  unsigned* gk = gkeys + (size_t)s * NELEM;

  __shared__ unsigned h[2048];
  h[2 * t] = 0u; h[2 * t + 1] = 0u;

  const int base = c * QC;
  float4 va0 = xq[base + t];
  float4 va1 = xq[base + t + 1024];
  float4 va2 = xq[base + t + 2048];
  const bool hast = t < (QC - 3072);   // 978
  float4 vt = hast ? xq[base + t + 3072] : va0;
  asm volatile("" :
      "+v"(va0.x), "+v"(va0.y), "+v"(va0.z), "+v"(va0.w),
      "+v"(va1.x), "+v"(va1.y), "+v"(va1.z), "+v"(va1.w),
      "+v"(va2.x), "+v"(va2.y), "+v"(va2.z), "+v"(va2.w),
      "+v"(vt.x), "+v"(vt.y), "+v"(vt.z), "+v"(vt.w));
  __syncthreads();

  { int g = base + t;        K1PROC(va0, g) }
  { int g = base + t + 1024; K1PROC(va1, g) }
  { int g = base + t + 2048; K1PROC(va2, g) }
  if (hast) { int g = base + t + 3072; K1PROC(vt, g) }
  __syncthreads();
  unsigned* gh = ghist + (size_t)blk * 2048;
  gh[2 * t] = h[2 * t];
  gh[2 * t + 1] = h[2 * t + 1];
}

// Wave-shuffle bucket select over hist[2048]. 16 waves x 128 buckets.
__device__ void select_bucket(const unsigned* hist, unsigned target,
                              volatile unsigned* chunkSuf,
                              unsigned* outB, unsigned* outCnt, unsigned* outAbove) {
  const int tid = threadIdx.x;
  const int w = tid >> 6, l = tid & 63;
  unsigned h1 = hist[w * 128 + 2 * l + 1];
  unsigned s = hist[w * 128 + 2 * l] + h1;
  #pragma unroll
  for (int d = 1; d < 64; d <<= 1) {
    unsigned t = __shfl_down(s, d);
    if (l + d < 64) s += t;
  }
  if (l == 0) chunkSuf[w] = s;
  __syncthreads();
  if (w == 0) {
    unsigned ct = (l < 16) ? chunkSuf[l] : 0u;
    unsigned cs = ct;
    #pragma unroll
    for (int d = 1; d < 16; d <<= 1) {
      unsigned t = __shfl_down(cs, d);
      if (l + d < 16) cs += t;
    }
    if (l < 16) chunkSuf[l] = cs - ct;
  }
  __syncthreads();
  unsigned base = chunkSuf[w];
  unsigned sufE = s + base;
  unsigned sN = __shfl_down(s, 1);
  unsigned sufN = ((l < 63) ? sN : 0u) + base;
  unsigned geOdd = sufN + h1;
  if (sufE >= target && geOdd < target) { *outB = w * 128u + 2u * l;     *outCnt = sufE;  *outAbove = geOdd; }
  if (geOdd >= target && sufN < target) { *outB = w * 128u + 2u * l + 1; *outCnt = geOdd; *outAbove = sufN;  }
  __syncthreads();
}

// ---------------- K2: exact top-1000 select + single-wave sort + NMS + output --
__global__ __launch_bounds__(NT, 4) void k2_main(
    const float* __restrict__ x, const float* __restrict__ anch,
    const unsigned* __restrict__ gkeys, const unsigned* __restrict__ ghist,
    float* __restrict__ out) {
  const int s = blockIdx.x;
  const int tid = threadIdx.x;
  const float* xb = x + (size_t)s * NELEM * 6;
  const unsigned* ks = gkeys + (size_t)s * NELEM;

  __shared__ unsigned hist[2048];
  __shared__ unsigned chunkSuf[16];
  __shared__ ull selPk[CAP];
  __shared__ float px1[1088], py1[1088], px2[1088], py2[1088], par[1088];
  __shared__ unsigned sB, sCnt, sAbove;
  __shared__ unsigned baseKey, cnt;
  __shared__ int keptRank[MAXB];
  __shared__ int numKept;

  // ---- issue the 21+1 key loads early (coalesced; drain at the pin) ----
  unsigned kv[NFULL];
  #pragma unroll
  for (int u = 0; u < NFULL; ++u) kv[u] = ks[tid + (u << 10)];
  unsigned ktail = 0u;
  const bool hastail = tid < NTAIL;
  if (hastail) ktail = ks[tid + NFULL * NT];

  // ---- sum the chunk histograms (overlaps with kv loads) ----
  {
    unsigned h0 = 0, h1 = 0;
    #pragma unroll
    for (int c = 0; c < NCHUNK; ++c) {
      const unsigned* gh = ghist + (size_t)(s * NCHUNK + c) * 2048;
      h0 += gh[2 * tid];
      h1 += gh[2 * tid + 1];
    }
    hist[2 * tid] = h0; hist[2 * tid + 1] = h1;
  }
  __syncthreads();
  select_bucket(hist, KSEL, chunkSuf, &sB, &sCnt, &sAbove);
  const unsigned b1 = sB, cnt1 = sCnt, above1 = sAbove;

  asm volatile("" :
      "+v"(kv[0]), "+v"(kv[1]), "+v"(kv[2]), "+v"(kv[3]), "+v"(kv[4]),
      "+v"(kv[5]), "+v"(kv[6]), "+v"(kv[7]), "+v"(kv[8]), "+v"(kv[9]),
      "+v"(kv[10]), "+v"(kv[11]), "+v"(kv[12]), "+v"(kv[13]), "+v"(kv[14]),
      "+v"(kv[15]), "+v"(kv[16]), "+v"(kv[17]), "+v"(kv[18]), "+v"(kv[19]),
      "+v"(kv[20]), "+v"(ktail));

  if (cnt1 > 1024) {
    // refine to 22 bits within bucket b1 so count fits the 1024 register sort
    hist[2 * tid] = 0u; hist[2 * tid + 1] = 0u;
    __syncthreads();
    #pragma unroll
    for (int u = 0; u < NFULL; ++u)
      if ((kv[u] >> 21) == b1) atomicAdd(&hist[(kv[u] >> 10) & 0x7FFu], 1u);
    if (hastail && (ktail >> 21) == b1) atomicAdd(&hist[(ktail >> 10) & 0x7FFu], 1u);
    __syncthreads();
    select_bucket(hist, KSEL - above1, chunkSuf, &sB, &sCnt, &sAbove);
    if (tid == 0) { baseKey = (b1 << 21) | (sB << 10); cnt = 0u; }
  } else {
    if (tid == 0) { baseKey = b1 << 21; cnt = 0u; }
  }
  __syncthreads();

  // ---- compact from registers: keys >= baseKey; wave-aggregated counter ----
  {
    const unsigned TB = baseKey;
    const int lw = tid & 63;
    #pragma unroll
    for (int u = 0; u < NFULL; ++u) {
      bool pred = kv[u] >= TB;
      ull mask = __ballot(pred);
      if (mask) {
        int leader = __builtin_ctzll(mask);
        unsigned total = (unsigned)__popcll(mask);
        unsigned basep = 0;
        if (lw == leader) basep = atomicAdd(&cnt, total);
        basep = __shfl(basep, leader);
        if (pred) {
          unsigned p = basep + (unsigned)__popcll(mask & ((1ull << lw) - 1ull));
          unsigned i = (unsigned)(tid + (u << 10));
          if (p < CAP) selPk[p] = ((ull)kv[u] << 32) | (unsigned)(~i);
        }
      }
    }
    if (hastail && ktail >= TB) {
      unsigned p = atomicAdd(&cnt, 1u);
      unsigned i = (unsigned)(tid + NFULL * NT);
      if (p < CAP) selPk[p] = ((ull)ktail << 32) | (unsigned)(~i);
    }
  }
  __syncthreads();
  const unsigned cntS = (cnt < CAP) ? cnt : CAP;
  for (unsigned i = cntS + tid; i < CAP; i += NT) selPk[i] = 0ull;
  __syncthreads();

  if (cntS <= 1024u) {
    // ---- single-wave in-register bitonic sort of 1024 (descending) ----
    // element e = r*64 + lane; j>=64 exchanges are register-register (free),
    // j<64 are shfl_xor. Zero barriers, one wave.
    if (tid < 64) {
      const int lane = tid;
      ull v[16];
      #pragma unroll
      for (int r = 0; r < 16; ++r) v[r] = selPk[(r << 6) | lane];
      #pragma unroll
      for (unsigned k = 2; k <= 1024; k <<= 1) {
        #pragma unroll
        for (unsigned j = k >> 1; j >= 1; j >>= 1) {
          if (j >= 64) {
            const int rb = (int)(j >> 6);
            #pragma unroll
            for (int r = 0; r < 16; ++r) {
              if ((r & rb) == 0) {
                const int r2 = r | rb;
                bool up = ((((unsigned)r << 6) & k) == 0);
                ull a = v[r], b = v[r2];
                ull mx = a > b ? a : b, mn = a > b ? b : a;
                v[r]  = up ? mx : mn;
                v[r2] = up ? mn : mx;
              }
            }
          } else {
            #pragma unroll
            for (int r = 0; r < 16; ++r) {
              unsigned e = ((unsigned)r << 6) | (unsigned)lane;
              bool up = ((e & k) == 0);
              bool lower = (((unsigned)lane & j) == 0);
              bool takeMax = (up == lower);
              ull o = __shfl_xor(v[r], (int)j);
              v[r] = takeMax ? (v[r] > o ? v[r] : o) : (v[r] < o ? v[r] : o);
            }
          }
        }
      }
      #pragma unroll
      for (int r = 0; r < 16; ++r) selPk[(r << 6) | lane] = v[r];
    }
    __syncthreads();
  } else {
    // ---- rare tie-heavy case: block-wide hybrid bitonic 2048 (proven) ----
    const int w = tid >> 6, L = tid & 63;
    const int ea = (w << 7) | (L << 1);
    ull a = selPk[ea], bb = selPk[ea + 1];
    #pragma unroll
    for (unsigned k = 2; k <= 128; k <<= 1) {
      #pragma unroll
      for (unsigned j = k >> 1; j >= 2; j >>= 1) {
        bool up = ((ea & k) == 0);
        bool lower = ((ea & j) == 0);
        bool takeMax = (up == lower);
        ull oa = __shfl_xor(a, (int)(j >> 1));
        ull ob = __shfl_xor(bb, (int)(j >> 1));
        a  = takeMax ? (a  > oa ? a  : oa) : (a  < oa ? a  : oa);
        bb = takeMax ? (bb > ob ? bb : ob) : (bb < ob ? bb : ob);
      }
      bool up = ((ea & k) == 0);
      ull mx = a > bb ? a : bb, mn = a > bb ? bb : a;
      a = up ? mx : mn; bb = up ? mn : mx;
    }
    selPk[ea] = a; selPk[ea + 1] = bb;
    __syncthreads();
    for (unsigned k = 256; k <= 2048; k <<= 1) {
      for (unsigned j = k >> 1; j >= 128; j >>= 1) {
        unsigned p = (unsigned)tid;
        unsigned vi = ((p & ~(j - 1)) << 1) | (p & (j - 1));
        unsigned li = vi | j;
        ull av = selPk[vi], cv = selPk[li];
        bool doswap = ((vi & k) == 0) ? (av < cv) : (av > cv);
        if (doswap) { selPk[vi] = cv; selPk[li] = av; }
        __syncthreads();
      }
      a = selPk[ea]; bb = selPk[ea + 1];
      bool up = (((unsigned)(w << 7) & k) == 0);
      #pragma unroll
      for (unsigned j = 64; j >= 2; j >>= 1) {
        bool lower = ((ea & j) == 0);
        bool takeMax = (up == lower);
        ull oa = __shfl_xor(a, (int)(j >> 1));
        ull ob = __shfl_xor(bb, (int)(j >> 1));
        a  = takeMax ? (a  > oa ? a  : oa) : (a  < oa ? a  : oa);
        bb = takeMax ? (bb > ob ? bb : ob) : (bb < ob ? bb : ob);
      }
      ull mx = a > bb ? a : bb, mn = a > bb ? bb : a;
      a = up ? mx : mn; bb = up ? mn : mx;
      selPk[ea] = a; selPk[ea + 1] = bb;
      __syncthreads();
    }
  }

  // ---- decode first 1000 into stride-17 box arrays ----
  if (tid < KSEL) {
    unsigned idx = ~(unsigned)selPk[tid];
    const float2* e2 = (const float2*)(xb + (size_t)idx * 6 + 2);
    float2 ra = e2[0], rb = e2[1];
    unsigned pp = (idx / 9u) % 60u;
    unsigned qq = idx / 540u;
    unsigned sr = idx % 9u;
    const float* ap = anch + (((pp * 40u + qq) * 9u + sr) * 4u);
    float ax = ap[0], ay = ap[1], aw = ap[2], ah = ap[3];
    float xc = ra.x * aw + ax;
    float yc = ra.y * ah + ay;
    float w = aw * expf(rb.x);
    float h = ah * expf(rb.y);
    float x1 = xc - 0.5f * w, x2 = xc + 0.5f * w;
    float y1 = yc - 0.5f * h, y2 = yc + 0.5f * h;
    int a = (tid >> 4) * 17 + (tid & 15);
    px1[a] = x1; py1[a] = y1; px2[a] = x2; py2[a] = y2;
    par[a] = (x2 - x1) * (y2 - y1);
  }
  __syncthreads();

  // ---- ballot-NMS on wave 0: 16 consecutive ranks per lane, exact over 1000 ----
  if (tid < 64) {
    const int lane = tid;
    float X1[16], Y1[16], X2[16], Y2[16], AR[16];
    unsigned alive = 0u;
    #pragma unroll
    for (int ss = 0; ss < 16; ++ss) {
      int r = lane * 16 + ss;
      int a = lane * 17 + ss;
      X1[ss] = px1[a]; Y1[ss] = py1[a];
      X2[ss] = px2[a]; Y2[ss] = py2[a]; AR[ss] = par[a];
      alive |= (r < KSEL ? 1u : 0u) << ss;
    }
    int nk = 0;
    while (nk < MAXB) {
      ull bal = __ballot(alive != 0u);
      if (!bal) break;
      int F = __builtin_ctzll(bal);
      int myss = (int)__builtin_ctz(alive | 0x10000u);
      int ssw = __shfl(myss, F);
      int m = F * 16 + ssw;
      if (lane == 0) keptRank[nk] = m;
      int am = (m >> 4) * 17 + (m & 15);
      float wx1 = px1[am], wy1 = py1[am], wx2 = px2[am], wy2 = py2[am];
      ++nk;
      if (nk >= MAXB) break;
      #pragma unroll
      for (int ss = 0; ss < 16; ++ss) {
        if (alive & (1u << ss)) {
          float iw = fmaxf(fminf(X2[ss], wx2) - fmaxf(X1[ss], wx1), 0.f);
          float ih = fmaxf(fminf(Y2[ss], wy2) - fmaxf(Y1[ss], wy1), 0.f);
          if (iw * ih / AR[ss] > 0.5f) alive &= ~(1u << ss);  // winner self-clears
        }
      }
    }
    if (lane == 0) numKept = nk;
  }
  __syncthreads();

  // ---- output: kept rows then pad rows cand[j - n]; score from key bits ----
  const int n = numKept;
  if (tid < MAXB) {
    int j = tid;
    int r = (j < n) ? keptRank[j] : (j - n);
    ull pk = selPk[r];
    unsigned idx = ~(unsigned)pk;
    float sc = unfkey((unsigned)(pk >> 32));
    const float2* e2 = (const float2*)(xb + (size_t)idx * 6 + 2);
    float2 ra = e2[0], rb = e2[1];
    unsigned pp = (idx / 9u) % 60u;
    unsigned qq = idx / 540u;
    unsigned sr = idx % 9u;
    const float* ap = anch + (((pp * 40u + qq) * 9u + sr) * 4u);
    float ax = ap[0], ay = ap[1], aw = ap[2], ah = ap[3];
    float xc = ra.x * aw + ax;
    float yc = ra.y * ah + ay;
    float w = aw * expf(rb.x);
    float h = ah * expf(rb.y);
    float* o = out + s * (MAXB * 5) + j * 5;
    o[0] = xc; o[1] = yc; o[2] = w; o[3] = h; o[4] = sc;
  }
}

extern "C" void kernel_launch(void* const* d_in, const int* in_sizes, int n_in,
                              void* d_out, int out_size, void* d_ws, size_t ws_size,
                              hipStream_t stream) {
  const float* x = (const float*)d_in[0];
  const float* anch = (const float*)d_in[1];
  float* out = (float*)d_out;
  const int B = in_sizes[0] / (NELEM * 6);
  unsigned* ghist = (unsigned*)d_ws;                         // B*8*2048 u32
  unsigned* gkeys = ghist + (size_t)B * NCHUNK * 2048;       // B*21600 u32
  k1_scan<<<dim3(B * NCHUNK), dim3(NT), 0, stream>>>(x, gkeys, ghist);
  k2_main<<<dim3(B), dim3(NT), 0, stream>>>(x, anch, gkeys, ghist, out);
}

// Round 11
// 82.754 us; speedup vs baseline: 1.0411x; 1.0411x over previous
//
#include <hip/hip_runtime.h>

#define NELEM 21600
#define KSEL 1000
#define MAXB 18
#define NT 1024
#define CAP 2048
#define NCHUNK 8
#define QC 4050                     // float4s per K1 block (32400/8)
#define NFULL 21                    // 21*1024 = 21504
#define NTAIL (NELEM - NFULL * NT)  // 96

typedef unsigned long long ull;

// monotone map: ascending uint key <-> ascending float
__device__ __forceinline__ unsigned fkey(float f) {
  unsigned u = __float_as_uint(f);
  return (u & 0x80000000u) ? ~u : (u | 0x80000000u);
}
__device__ __forceinline__ float unfkey(unsigned k) {
  unsigned u = (k & 0x80000000u) ? (k ^ 0x80000000u) : ~k;
  return __uint_as_float(u);
}

#define K1PROC(v, g) { int r = (g) % 3; \
  if (r == 0) { unsigned key = fkey((v).x); gk[2 * ((g) / 3)] = key; atomicAdd(&h[key >> 21], 1u); } \
  else if (r == 1) { unsigned key = fkey((v).z); gk[2 * ((g) / 3) + 1] = key; atomicAdd(&h[key >> 21], 1u); } }

// ---------------- K1: full-chip float4-coalesced scan -> keys + chunk hists ----
__global__ __launch_bounds__(NT) void k1_scan(
    const float* __restrict__ x, unsigned* __restrict__ gkeys,
    unsigned* __restrict__ ghist) {
  const int blk = blockIdx.x;
  const int s = blk / NCHUNK, c = blk % NCHUNK;
  const int t = threadIdx.x;
  const float4* xq = (const float4*)(x + (size_t)s * NELEM * 6);
  unsigned* gk = gkeys + (size_t)s * NELEM;

  __shared__ unsigned h[2048];
  h[2 * t] = 0u; h[2 * t + 1] = 0u;

  const int base = c * QC;
  float4 va0 = xq[base + t];
  float4 va1 = xq[base + t + 1024];
  float4 va2 = xq[base + t + 2048];
  const bool hast = t < (QC - 3072);   // 978
  float4 vt = hast ? xq[base + t + 3072] : va0;
  asm volatile("" :
      "+v"(va0.x), "+v"(va0.y), "+v"(va0.z), "+v"(va0.w),
      "+v"(va1.x), "+v"(va1.y), "+v"(va1.z), "+v"(va1.w),
      "+v"(va2.x), "+v"(va2.y), "+v"(va2.z), "+v"(va2.w),
      "+v"(vt.x), "+v"(vt.y), "+v"(vt.z), "+v"(vt.w));
  __syncthreads();

  { int g = base + t;        K1PROC(va0, g) }
  { int g = base + t + 1024; K1PROC(va1, g) }
  { int g = base + t + 2048; K1PROC(va2, g) }
  if (hast) { int g = base + t + 3072; K1PROC(vt, g) }
  __syncthreads();
  unsigned* gh = ghist + (size_t)blk * 2048;
  gh[2 * t] = h[2 * t];
  gh[2 * t + 1] = h[2 * t + 1];
}

// Wave-shuffle bucket select over hist[2048]. 16 waves x 128 buckets.
__device__ void select_bucket(const unsigned* hist, unsigned target,
                              volatile unsigned* chunkSuf,
                              unsigned* outB, unsigned* outCnt, unsigned* outAbove) {
  const int tid = threadIdx.x;
  const int w = tid >> 6, l = tid & 63;
  unsigned h1 = hist[w * 128 + 2 * l + 1];
  unsigned s = hist[w * 128 + 2 * l] + h1;
  #pragma unroll
  for (int d = 1; d < 64; d <<= 1) {
    unsigned t = __shfl_down(s, d);
    if (l + d < 64) s += t;
  }
  if (l == 0) chunkSuf[w] = s;
  __syncthreads();
  if (w == 0) {
    unsigned ct = (l < 16) ? chunkSuf[l] : 0u;
    unsigned cs = ct;
    #pragma unroll
    for (int d = 1; d < 16; d <<= 1) {
      unsigned t = __shfl_down(cs, d);
      if (l + d < 16) cs += t;
    }
    if (l < 16) chunkSuf[l] = cs - ct;
  }
  __syncthreads();
  unsigned base = chunkSuf[w];
  unsigned sufE = s + base;
  unsigned sN = __shfl_down(s, 1);
  unsigned sufN = ((l < 63) ? sN : 0u) + base;
  unsigned geOdd = sufN + h1;
  if (sufE >= target && geOdd < target) { *outB = w * 128u + 2u * l;     *outCnt = sufE;  *outAbove = geOdd; }
  if (geOdd >= target && sufN < target) { *outB = w * 128u + 2u * l + 1; *outCnt = geOdd; *outAbove = sufN;  }
  __syncthreads();
}

// ---- wave-0 NMS, 16 reg slots/lane (common path, cnt <= 1024) ----
__device__ void nms16(const ull* selPk, const float* bx1, const float* by1,
                      const float* bx2, const float* by2, unsigned cntS,
                      ull* keptPk, int* numKept) {
  const int lane = threadIdx.x;
  ull pk[16];
  float X1[16], Y1[16], X2[16], Y2[16];
  unsigned alive = 0u;
  #pragma unroll
  for (int k = 0; k < 16; ++k) {
    int sl = (k << 6) | lane;
    pk[k] = selPk[sl];
    X1[k] = bx1[sl]; Y1[k] = by1[sl]; X2[k] = bx2[sl]; Y2[k] = by2[sl];
    alive |= (sl < (int)cntS ? 1u : 0u) << k;
  }
  int nk = 0;
  while (nk < MAXB) {
    ull bp = 0ull;
    float w1 = 0.f, w2 = 0.f, w3 = 0.f, w4 = 0.f;
    #pragma unroll
    for (int k = 0; k < 16; ++k) {
      bool t = ((alive >> k) & 1u) && (pk[k] > bp);
      if (t) { bp = pk[k]; w1 = X1[k]; w2 = Y1[k]; w3 = X2[k]; w4 = Y2[k]; }
    }
    #pragma unroll
    for (int d = 1; d < 64; d <<= 1) {
      ull op = __shfl_xor(bp, d);
      float o1 = __shfl_xor(w1, d), o2 = __shfl_xor(w2, d);
      float o3 = __shfl_xor(w3, d), o4 = __shfl_xor(w4, d);
      if (op > bp) { bp = op; w1 = o1; w2 = o2; w3 = o3; w4 = o4; }
    }
    if (bp == 0ull) break;
    if (lane == 0) keptPk[nk] = bp;
    ++nk;
    if (nk >= MAXB) break;
    #pragma unroll
    for (int k = 0; k < 16; ++k) {
      if ((alive >> k) & 1u) {
        float iw = fmaxf(fminf(X2[k], w3) - fmaxf(X1[k], w1), 0.f);
        float ih = fmaxf(fminf(Y2[k], w4) - fmaxf(Y1[k], w2), 0.f);
        float ar = (X2[k] - X1[k]) * (Y2[k] - Y1[k]);
        if (iw * ih / ar > 0.5f) alive &= ~(1u << k);   // winner self-clears (ratio==1)
      }
    }
  }
  if (lane == 0) *numKept = nk;
}

// ---- wave-1 pure top-18 extraction, 16 reg slots/lane ----
__device__ void pure16(const ull* selPk, unsigned cntS, ull* purePk) {
  const int lane = threadIdx.x - 64;
  ull pk[16];
  unsigned alive = 0u;
  #pragma unroll
  for (int k = 0; k < 16; ++k) {
    int sl = (k << 6) | lane;
    pk[k] = selPk[sl];
    alive |= (sl < (int)cntS ? 1u : 0u) << k;
  }
  for (int t = 0; t < MAXB; ++t) {
    ull bp = 0ull;
    #pragma unroll
    for (int k = 0; k < 16; ++k) {
      bool tk = ((alive >> k) & 1u) && (pk[k] > bp);
      if (tk) bp = pk[k];
    }
    #pragma unroll
    for (int d = 1; d < 64; d <<= 1) {
      ull op = __shfl_xor(bp, d);
      if (op > bp) bp = op;
    }
    if (lane == 0) purePk[t] = bp;
    #pragma unroll
    for (int k = 0; k < 16; ++k)
      if (pk[k] == bp) alive &= ~(1u << k);
  }
}

// ---- rare fallback (1024 < cnt <= 2048): 32 slots/lane, coords from LDS ----
__device__ void nms32(const ull* selPk, const float* bx1, const float* by1,
                      const float* bx2, const float* by2, unsigned cntS,
                      ull* keptPk, int* numKept) {
  const int lane = threadIdx.x;
  ull pk[32];
  unsigned alive = 0u;
  #pragma unroll
  for (int k = 0; k < 32; ++k) {
    int sl = (k << 6) | lane;
    pk[k] = selPk[sl];
    alive |= (sl < (int)cntS ? 1u : 0u) << k;
  }
  int nk = 0;
  while (nk < MAXB) {
    ull bp = 0ull;
    int bs = lane;
    #pragma unroll
    for (int k = 0; k < 32; ++k) {
      bool t = ((alive >> k) & 1u) && (pk[k] > bp);
      if (t) { bp = pk[k]; bs = (k << 6) | lane; }
    }
    float w1 = bx1[bs], w2 = by1[bs], w3 = bx2[bs], w4 = by2[bs];
    #pragma unroll
    for (int d = 1; d < 64; d <<= 1) {
      ull op = __shfl_xor(bp, d);
      float o1 = __shfl_xor(w1, d), o2 = __shfl_xor(w2, d);
      float o3 = __shfl_xor(w3, d), o4 = __shfl_xor(w4, d);
      if (op > bp) { bp = op; w1 = o1; w2 = o2; w3 = o3; w4 = o4; }
    }
    if (bp == 0ull) break;
    if (lane == 0) keptPk[nk] = bp;
    ++nk;
    if (nk >= MAXB) break;
    #pragma unroll
    for (int k = 0; k < 32; ++k) {
      if ((alive >> k) & 1u) {
        int sl = (k << 6) | lane;
        float x1 = bx1[sl], y1 = by1[sl], x2 = bx2[sl], y2 = by2[sl];
        float iw = fmaxf(fminf(x2, w3) - fmaxf(x1, w1), 0.f);
        float ih = fmaxf(fminf(y2, w4) - fmaxf(y1, w2), 0.f);
        float ar = (x2 - x1) * (y2 - y1);
        if (iw * ih / ar > 0.5f) alive &= ~(1u << k);
      }
    }
  }
  if (lane == 0) *numKept = nk;
}

__device__ void pure32(const ull* selPk, unsigned cntS, ull* purePk) {
  const int lane = threadIdx.x - 64;
  ull pk[32];
  unsigned alive = 0u;
  #pragma unroll
  for (int k = 0; k < 32; ++k) {
    int sl = (k << 6) | lane;
    pk[k] = selPk[sl];
    alive |= (sl < (int)cntS ? 1u : 0u) << k;
  }
  for (int t = 0; t < MAXB; ++t) {
    ull bp = 0ull;
    #pragma unroll
    for (int k = 0; k < 32; ++k) {
      bool tk = ((alive >> k) & 1u) && (pk[k] > bp);
      if (tk) bp = pk[k];
    }
    #pragma unroll
    for (int d = 1; d < 64; d <<= 1) {
      ull op = __shfl_xor(bp, d);
      if (op > bp) bp = op;
    }
    if (lane == 0) purePk[t] = bp;
    #pragma unroll
    for (int k = 0; k < 32; ++k)
      if (pk[k] == bp) alive &= ~(1u << k);
  }
}

// ---------------- K2: select + compact + decode + sortless NMS + output --------
__global__ __launch_bounds__(NT, 4) void k2_main(
    const float* __restrict__ x, const float* __restrict__ anch,
    const unsigned* __restrict__ gkeys, const unsigned* __restrict__ ghist,
    float* __restrict__ out) {
  const int s = blockIdx.x;
  const int tid = threadIdx.x;
  const float* xb = x + (size_t)s * NELEM * 6;
  const unsigned* ks = gkeys + (size_t)s * NELEM;

  __shared__ unsigned hist[2048];
  __shared__ unsigned chunkSuf[16];
  __shared__ ull selPk[CAP];
  __shared__ float bx1[CAP], by1[CAP], bx2[CAP], by2[CAP];
  __shared__ unsigned sB, sCnt, sAbove;
  __shared__ unsigned baseKey, cnt;
  __shared__ ull keptPk[MAXB];
  __shared__ ull purePk[MAXB];
  __shared__ int numKept;

  // ---- issue the 21+1 key loads early (coalesced; drain at the pin) ----
  unsigned kv[NFULL];
  #pragma unroll
  for (int u = 0; u < NFULL; ++u) kv[u] = ks[tid + (u << 10)];
  unsigned ktail = 0u;
  const bool hastail = tid < NTAIL;
  if (hastail) ktail = ks[tid + NFULL * NT];

  // ---- sum the chunk histograms (overlaps with kv loads) ----
  {
    unsigned h0 = 0, h1 = 0;
    #pragma unroll
    for (int c = 0; c < NCHUNK; ++c) {
      const unsigned* gh = ghist + (size_t)(s * NCHUNK + c) * 2048;
      h0 += gh[2 * tid];
      h1 += gh[2 * tid + 1];
    }
    hist[2 * tid] = h0; hist[2 * tid + 1] = h1;
  }
  __syncthreads();
  select_bucket(hist, KSEL, chunkSuf, &sB, &sCnt, &sAbove);
  const unsigned b1 = sB, cnt1 = sCnt, above1 = sAbove;

  asm volatile("" :
      "+v"(kv[0]), "+v"(kv[1]), "+v"(kv[2]), "+v"(kv[3]), "+v"(kv[4]),
      "+v"(kv[5]), "+v"(kv[6]), "+v"(kv[7]), "+v"(kv[8]), "+v"(kv[9]),
      "+v"(kv[10]), "+v"(kv[11]), "+v"(kv[12]), "+v"(kv[13]), "+v"(kv[14]),
      "+v"(kv[15]), "+v"(kv[16]), "+v"(kv[17]), "+v"(kv[18]), "+v"(kv[19]),
      "+v"(kv[20]), "+v"(ktail));

  if (cnt1 > 1024) {
    // refine to 22 bits so the common path fits 16 slots/lane
    hist[2 * tid] = 0u; hist[2 * tid + 1] = 0u;
    __syncthreads();
    #pragma unroll
    for (int u = 0; u < NFULL; ++u)
      if ((kv[u] >> 21) == b1) atomicAdd(&hist[(kv[u] >> 10) & 0x7FFu], 1u);
    if (hastail && (ktail >> 21) == b1) atomicAdd(&hist[(ktail >> 10) & 0x7FFu], 1u);
    __syncthreads();
    select_bucket(hist, KSEL - above1, chunkSuf, &sB, &sCnt, &sAbove);
    if (tid == 0) { baseKey = (b1 << 21) | (sB << 10); cnt = 0u; }
  } else {
    if (tid == 0) { baseKey = b1 << 21; cnt = 0u; }
  }
  __syncthreads();

  // ---- compact from registers: keys >= baseKey; wave-aggregated counter ----
  {
    const unsigned TB = baseKey;
    const int lw = tid & 63;
    #pragma unroll
    for (int u = 0; u < NFULL; ++u) {
      bool pred = kv[u] >= TB;
      ull mask = __ballot(pred);
      if (mask) {
        int leader = __builtin_ctzll(mask);
        unsigned total = (unsigned)__popcll(mask);
        unsigned basep = 0;
        if (lw == leader) basep = atomicAdd(&cnt, total);
        basep = __shfl(basep, leader);
        if (pred) {
          unsigned p = basep + (unsigned)__popcll(mask & ((1ull << lw) - 1ull));
          unsigned i = (unsigned)(tid + (u << 10));
          if (p < CAP) selPk[p] = ((ull)kv[u] << 32) | (unsigned)(~i);
        }
      }
    }
    if (hastail && ktail >= TB) {
      unsigned p = atomicAdd(&cnt, 1u);
      unsigned i = (unsigned)(tid + NFULL * NT);
      if (p < CAP) selPk[p] = ((ull)ktail << 32) | (unsigned)(~i);
    }
  }
  __syncthreads();
  const unsigned cntS = (cnt < CAP) ? cnt : CAP;
  for (unsigned i = cntS + tid; i < CAP; i += NT) selPk[i] = 0ull;
  __syncthreads();

  // ---- decode all cntS candidates into plain LDS box arrays ----
  for (unsigned i = tid; i < cntS; i += NT) {
    unsigned idx = ~(unsigned)selPk[i];
    const float2* e2 = (const float2*)(xb + (size_t)idx * 6 + 2);
    float2 ra = e2[0], rb = e2[1];
    unsigned pp = (idx / 9u) % 60u;
    unsigned qq = idx / 540u;
    unsigned sr = idx % 9u;
    const float* ap = anch + (((pp * 40u + qq) * 9u + sr) * 4u);
    float ax = ap[0], ay = ap[1], aw = ap[2], ah = ap[3];
    float xc = ra.x * aw + ax;
    float yc = ra.y * ah + ay;
    float w = aw * expf(rb.x);
    float h = ah * expf(rb.y);
    bx1[i] = xc - 0.5f * w; bx2[i] = xc + 0.5f * w;
    by1[i] = yc - 0.5f * h; by2[i] = yc + 0.5f * h;
  }
  __syncthreads();

  // ---- wave 0: greedy NMS; wave 1: pure top-18 (concurrent) ----
  if (cntS <= 1024u) {
    if (tid < 64) nms16(selPk, bx1, by1, bx2, by2, cntS, keptPk, &numKept);
    else if (tid < 128) pure16(selPk, cntS, purePk);
  } else {
    if (tid < 64) nms32(selPk, bx1, by1, bx2, by2, cntS, keptPk, &numKept);
    else if (tid < 128) pure32(selPk, cntS, purePk);
  }
  __syncthreads();

  // ---- output: kept rows then pad rows cand[j - n]; score from key bits ----
  const int n = numKept;
  if (tid < MAXB) {
    int j = tid;
    ull pk = (j < n) ? keptPk[j] : purePk[j - n];
    unsigned idx = ~(unsigned)pk;
    float sc = unfkey((unsigned)(pk >> 32));
    const float2* e2 = (const float2*)(xb + (size_t)idx * 6 + 2);
    float2 ra = e2[0], rb = e2[1];
    unsigned pp = (idx / 9u) % 60u;
    unsigned qq = idx / 540u;
    unsigned sr = idx % 9u;
    const float* ap = anch + (((pp * 40u + qq) * 9u + sr) * 4u);
    float ax = ap[0], ay = ap[1], aw = ap[2], ah = ap[3];
    float xc = ra.x * aw + ax;
    float yc = ra.y * ah + ay;
    float w = aw * expf(rb.x);
    float h = ah * expf(rb.y);
    float* o = out + s * (MAXB * 5) + j * 5;
    o[0] = xc; o[1] = yc; o[2] = w; o[3] = h; o[4] = sc;
  }
}

extern "C" void kernel_launch(void* const* d_in, const int* in_sizes, int n_in,
                              void* d_out, int out_size, void* d_ws, size_t ws_size,
                              hipStream_t stream) {
  const float* x = (const float*)d_in[0];
  const float* anch = (const float*)d_in[1];
  float* out = (float*)d_out;
  const int B = in_sizes[0] / (NELEM * 6);
  unsigned* ghist = (unsigned*)d_ws;                         // B*8*2048 u32
  unsigned* gkeys = ghist + (size_t)B * NCHUNK * 2048;       // B*21600 u32
  k1_scan<<<dim3(B * NCHUNK), dim3(NT), 0, stream>>>(x, gkeys, ghist);
  k2_main<<<dim3(B), dim3(NT), 0, stream>>>(x, anch, gkeys, ghist, out);
}

// Round 12
// 65.145 us; speedup vs baseline: 1.3225x; 1.2703x over previous
//
#include <hip/hip_runtime.h>

#define NELEM 21600
#define KSEL 1000
#define MAXB 18
#define NT 1024
#define CAP 2048
#define NCHUNK 8
#define QC 4050                     // float4s per K1 block (32400/8)
#define NFULL 21                    // 21*1024 = 21504
#define NTAIL (NELEM - NFULL * NT)  // 96

typedef unsigned long long ull;

// monotone map: ascending uint key <-> ascending float
__device__ __forceinline__ unsigned fkey(float f) {
  unsigned u = __float_as_uint(f);
  return (u & 0x80000000u) ? ~u : (u | 0x80000000u);
}
__device__ __forceinline__ float unfkey(unsigned k) {
  unsigned u = (k & 0x80000000u) ? (k ^ 0x80000000u) : ~k;
  return __uint_as_float(u);
}

#define K1PROC(v, g) { int r = (g) % 3; \
  if (r == 0) { unsigned key = fkey((v).x); gk[2 * ((g) / 3)] = key; atomicAdd(&h[key >> 21], 1u); } \
  else if (r == 1) { unsigned key = fkey((v).z); gk[2 * ((g) / 3) + 1] = key; atomicAdd(&h[key >> 21], 1u); } }

// ---------------- K1: full-chip float4-coalesced scan -> keys + chunk hists ----
__global__ __launch_bounds__(NT) void k1_scan(
    const float* __restrict__ x, unsigned* __restrict__ gkeys,
    unsigned* __restrict__ ghist) {
  const int blk = blockIdx.x;
  const int s = blk / NCHUNK, c = blk % NCHUNK;
  const int t = threadIdx.x;
  const float4* xq = (const float4*)(x + (size_t)s * NELEM * 6);
  unsigned* gk = gkeys + (size_t)s * NELEM;

  __shared__ unsigned h[2048];
  h[2 * t] = 0u; h[2 * t + 1] = 0u;

  const int base = c * QC;
  float4 va0 = xq[base + t];
  float4 va1 = xq[base + t + 1024];
  float4 va2 = xq[base + t + 2048];
  const bool hast = t < (QC - 3072);   // 978
  float4 vt = hast ? xq[base + t + 3072] : va0;
  asm volatile("" :
      "+v"(va0.x), "+v"(va0.y), "+v"(va0.z), "+v"(va0.w),
      "+v"(va1.x), "+v"(va1.y), "+v"(va1.z), "+v"(va1.w),
      "+v"(va2.x), "+v"(va2.y), "+v"(va2.z), "+v"(va2.w),
      "+v"(vt.x), "+v"(vt.y), "+v"(vt.z), "+v"(vt.w));
  __syncthreads();

  { int g = base + t;        K1PROC(va0, g) }
  { int g = base + t + 1024; K1PROC(va1, g) }
  { int g = base + t + 2048; K1PROC(va2, g) }
  if (hast) { int g = base + t + 3072; K1PROC(vt, g) }
  __syncthreads();
  unsigned* gh = ghist + (size_t)blk * 2048;
  gh[2 * t] = h[2 * t];
  gh[2 * t + 1] = h[2 * t + 1];
}

// Wave-shuffle bucket select over hist[2048]. 16 waves x 128 buckets.
__device__ void select_bucket(const unsigned* hist, unsigned target,
                              volatile unsigned* chunkSuf,
                              unsigned* outB, unsigned* outCnt, unsigned* outAbove) {
  const int tid = threadIdx.x;
  const int w = tid >> 6, l = tid & 63;
  unsigned h1 = hist[w * 128 + 2 * l + 1];
  unsigned s = hist[w * 128 + 2 * l] + h1;
  #pragma unroll
  for (int d = 1; d < 64; d <<= 1) {
    unsigned t = __shfl_down(s, d);
    if (l + d < 64) s += t;
  }
  if (l == 0) chunkSuf[w] = s;
  __syncthreads();
  if (w == 0) {
    unsigned ct = (l < 16) ? chunkSuf[l] : 0u;
    unsigned cs = ct;
    #pragma unroll
    for (int d = 1; d < 16; d <<= 1) {
      unsigned t = __shfl_down(cs, d);
      if (l + d < 16) cs += t;
    }
    if (l < 16) chunkSuf[l] = cs - ct;
  }
  __syncthreads();
  unsigned base = chunkSuf[w];
  unsigned sufE = s + base;
  unsigned sN = __shfl_down(s, 1);
  unsigned sufN = ((l < 63) ? sN : 0u) + base;
  unsigned geOdd = sufN + h1;
  if (sufE >= target && geOdd < target) { *outB = w * 128u + 2u * l;     *outCnt = sufE;  *outAbove = geOdd; }
  if (geOdd >= target && sufN < target) { *outB = w * 128u + 2u * l + 1; *outCnt = geOdd; *outAbove = sufN;  }
  __syncthreads();
}

// ---------------- K2: select + compact + sort + LDS-NMS + output ---------------
__global__ __launch_bounds__(NT, 4) void k2_main(
    const float* __restrict__ x, const float* __restrict__ anch,
    const unsigned* __restrict__ gkeys, const unsigned* __restrict__ ghist,
    float* __restrict__ out) {
  const int s = blockIdx.x;
  const int tid = threadIdx.x;
  const float* xb = x + (size_t)s * NELEM * 6;
  const unsigned* ks = gkeys + (size_t)s * NELEM;

  __shared__ unsigned hist[2048];
  __shared__ unsigned chunkSuf[16];
  __shared__ ull selPk[CAP];
  __shared__ float px1[1088], py1[1088], px2[1088], py2[1088];
  __shared__ unsigned sB, sCnt, sAbove;
  __shared__ unsigned baseKey, cnt;
  __shared__ int keptRank[MAXB];
  __shared__ int numKept;

  // ---- issue the 21+1 key loads early (coalesced; drain at the pin) ----
  unsigned kv[NFULL];
  #pragma unroll
  for (int u = 0; u < NFULL; ++u) kv[u] = ks[tid + (u << 10)];
  unsigned ktail = 0u;
  const bool hastail = tid < NTAIL;
  if (hastail) ktail = ks[tid + NFULL * NT];

  // ---- sum the chunk histograms (overlaps with kv loads) ----
  {
    unsigned h0 = 0, h1 = 0;
    #pragma unroll
    for (int c = 0; c < NCHUNK; ++c) {
      const unsigned* gh = ghist + (size_t)(s * NCHUNK + c) * 2048;
      h0 += gh[2 * tid];
      h1 += gh[2 * tid + 1];
    }
    hist[2 * tid] = h0; hist[2 * tid + 1] = h1;
  }
  __syncthreads();
  select_bucket(hist, KSEL, chunkSuf, &sB, &sCnt, &sAbove);
  const unsigned b1 = sB, cnt1 = sCnt, above1 = sAbove;

  asm volatile("" :
      "+v"(kv[0]), "+v"(kv[1]), "+v"(kv[2]), "+v"(kv[3]), "+v"(kv[4]),
      "+v"(kv[5]), "+v"(kv[6]), "+v"(kv[7]), "+v"(kv[8]), "+v"(kv[9]),
      "+v"(kv[10]), "+v"(kv[11]), "+v"(kv[12]), "+v"(kv[13]), "+v"(kv[14]),
      "+v"(kv[15]), "+v"(kv[16]), "+v"(kv[17]), "+v"(kv[18]), "+v"(kv[19]),
      "+v"(kv[20]), "+v"(ktail));

  if (cnt1 > 1024) {
    // refine to 22 bits so the common path fits the 1024 sort
    hist[2 * tid] = 0u; hist[2 * tid + 1] = 0u;
    __syncthreads();
    #pragma unroll
    for (int u = 0; u < NFULL; ++u)
      if ((kv[u] >> 21) == b1) atomicAdd(&hist[(kv[u] >> 10) & 0x7FFu], 1u);
    if (hastail && (ktail >> 21) == b1) atomicAdd(&hist[(ktail >> 10) & 0x7FFu], 1u);
    __syncthreads();
    select_bucket(hist, KSEL - above1, chunkSuf, &sB, &sCnt, &sAbove);
    if (tid == 0) { baseKey = (b1 << 21) | (sB << 10); cnt = 0u; }
  } else {
    if (tid == 0) { baseKey = b1 << 21; cnt = 0u; }
  }
  __syncthreads();

  // ---- compact from registers: keys >= baseKey; wave-aggregated counter ----
  {
    const unsigned TB = baseKey;
    const int lw = tid & 63;
    #pragma unroll
    for (int u = 0; u < NFULL; ++u) {
      bool pred = kv[u] >= TB;
      ull mask = __ballot(pred);
      if (mask) {
        int leader = __builtin_ctzll(mask);
        unsigned total = (unsigned)__popcll(mask);
        unsigned basep = 0;
        if (lw == leader) basep = atomicAdd(&cnt, total);
        basep = __shfl(basep, leader);
        if (pred) {
          unsigned p = basep + (unsigned)__popcll(mask & ((1ull << lw) - 1ull));
          unsigned i = (unsigned)(tid + (u << 10));
          if (p < CAP) selPk[p] = ((ull)kv[u] << 32) | (unsigned)(~i);
        }
      }
    }
    if (hastail && ktail >= TB) {
      unsigned p = atomicAdd(&cnt, 1u);
      unsigned i = (unsigned)(tid + NFULL * NT);
      if (p < CAP) selPk[p] = ((ull)ktail << 32) | (unsigned)(~i);
    }
  }
  __syncthreads();
  const unsigned cntS = (cnt < CAP) ? cnt : CAP;
  const unsigned P = (cntS <= 1024u) ? 1024u : 2048u;
  for (unsigned i = cntS + tid; i < P; i += NT) selPk[i] = 0ull;
  __syncthreads();

  if (P == 1024u) {
    // ---- hybrid bitonic sort 1024 descending, 1 elem/thread (2 VGPR) ----
    ull a = selPk[tid];
    #pragma unroll
    for (unsigned k = 2; k <= 64; k <<= 1) {
      #pragma unroll
      for (unsigned j = k >> 1; j >= 1; j >>= 1) {
        bool up = ((tid & k) == 0);
        bool lower = ((tid & j) == 0);
        bool takeMax = (up == lower);
        ull o = __shfl_xor(a, (int)j);
        a = takeMax ? (a > o ? a : o) : (a < o ? a : o);
      }
    }
    selPk[tid] = a;
    __syncthreads();
    for (unsigned k = 128; k <= 1024; k <<= 1) {
      for (unsigned j = k >> 1; j >= 64; j >>= 1) {
        if (tid < 512) {
          unsigned p = (unsigned)tid;
          unsigned vi = ((p & ~(j - 1)) << 1) | (p & (j - 1));
          unsigned li = vi | j;
          ull av = selPk[vi], cv = selPk[li];
          bool doswap = ((vi & k) == 0) ? (av < cv) : (av > cv);
          if (doswap) { selPk[vi] = cv; selPk[li] = av; }
        }
        __syncthreads();
      }
      a = selPk[tid];
      {
        bool up = ((tid & k) == 0);
        #pragma unroll
        for (unsigned j = 32; j >= 1; j >>= 1) {
          bool lower = ((tid & j) == 0);
          bool takeMax = (up == lower);
          ull o = __shfl_xor(a, (int)j);
          a = takeMax ? (a > o ? a : o) : (a < o ? a : o);
        }
      }
      selPk[tid] = a;
      __syncthreads();
    }
  } else {
    // ---- rare tie-heavy case: hybrid bitonic 2048, 2 elem/thread ----
    const int w = tid >> 6, L = tid & 63;
    const int ea = (w << 7) | (L << 1);
    ull a = selPk[ea], bb = selPk[ea + 1];
    #pragma unroll
    for (unsigned k = 2; k <= 128; k <<= 1) {
      #pragma unroll
      for (unsigned j = k >> 1; j >= 2; j >>= 1) {
        bool up = ((ea & k) == 0);
        bool lower = ((ea & j) == 0);
        bool takeMax = (up == lower);
        ull oa = __shfl_xor(a, (int)(j >> 1));
        ull ob = __shfl_xor(bb, (int)(j >> 1));
        a  = takeMax ? (a  > oa ? a  : oa) : (a  < oa ? a  : oa);
        bb = takeMax ? (bb > ob ? bb : ob) : (bb < ob ? bb : ob);
      }
      bool up = ((ea & k) == 0);
      ull mx = a > bb ? a : bb, mn = a > bb ? bb : a;
      a = up ? mx : mn; bb = up ? mn : mx;
    }
    selPk[ea] = a; selPk[ea + 1] = bb;
    __syncthreads();
    for (unsigned k = 256; k <= 2048; k <<= 1) {
      for (unsigned j = k >> 1; j >= 128; j >>= 1) {
        unsigned p = (unsigned)tid;
        unsigned vi = ((p & ~(j - 1)) << 1) | (p & (j - 1));
        unsigned li = vi | j;
        ull av = selPk[vi], cv = selPk[li];
        bool doswap = ((vi & k) == 0) ? (av < cv) : (av > cv);
        if (doswap) { selPk[vi] = cv; selPk[li] = av; }
        __syncthreads();
      }
      a = selPk[ea]; bb = selPk[ea + 1];
      bool up = (((unsigned)(w << 7) & k) == 0);
      #pragma unroll
      for (unsigned j = 64; j >= 2; j >>= 1) {
        bool lower = ((ea & j) == 0);
        bool takeMax = (up == lower);
        ull oa = __shfl_xor(a, (int)(j >> 1));
        ull ob = __shfl_xor(bb, (int)(j >> 1));
        a  = takeMax ? (a  > oa ? a  : oa) : (a  < oa ? a  : oa);
        bb = takeMax ? (bb > ob ? bb : ob) : (bb < ob ? bb : ob);
      }
      ull mx = a > bb ? a : bb, mn = a > bb ? bb : a;
      a = up ? mx : mn; bb = up ? mn : mx;
      selPk[ea] = a; selPk[ea + 1] = bb;
      __syncthreads();
    }
  }

  // ---- decode first 1000 into stride-17 scalar LDS arrays (conflict-free) ----
  if (tid < KSEL) {
    unsigned idx = ~(unsigned)selPk[tid];
    const float2* e2 = (const float2*)(xb + (size_t)idx * 6 + 2);
    float2 ra = e2[0], rb = e2[1];
    unsigned pp = (idx / 9u) % 60u;
    unsigned qq = idx / 540u;
    unsigned sr = idx % 9u;
    const float* ap = anch + (((pp * 40u + qq) * 9u + sr) * 4u);
    float ax = ap[0], ay = ap[1], aw = ap[2], ah = ap[3];
    float xc = ra.x * aw + ax;
    float yc = ra.y * ah + ay;
    float w = aw * expf(rb.x);
    float h = ah * expf(rb.y);
    int a = (tid >> 4) * 17 + (tid & 15);
    px1[a] = xc - 0.5f * w; px2[a] = xc + 0.5f * w;
    py1[a] = yc - 0.5f * h; py2[a] = yc + 0.5f * h;
  }
  __syncthreads();

  // ---- ballot-NMS on wave 0: coords read from LDS, tiny register state ----
  if (tid < 64) {
    const int lane = tid;
    unsigned alive = 0u;
    #pragma unroll
    for (int ss = 0; ss < 16; ++ss) {
      int r = lane * 16 + ss;
      alive |= (r < KSEL ? 1u : 0u) << ss;
    }
    int nk = 0;
    while (nk < MAXB) {
      ull bal = __ballot(alive != 0u);
      if (!bal) break;
      int F = __builtin_ctzll(bal);                 // lane holding best alive
      int myss = (int)__builtin_ctz(alive | 0x10000u);
      int ssw = __shfl(myss, F);
      int m = F * 16 + ssw;                         // global rank of winner
      if (lane == 0) keptRank[nk] = m;
      int am = (m >> 4) * 17 + (m & 15);
      float wx1 = px1[am], wy1 = py1[am], wx2 = px2[am], wy2 = py2[am];
      ++nk;
      if (nk >= MAXB) break;
      #pragma unroll
      for (int ss = 0; ss < 16; ++ss) {
        if (alive & (1u << ss)) {
          int a = lane * 17 + ss;
          float x1 = px1[a], y1 = py1[a], x2 = px2[a], y2 = py2[a];
          float iw = fmaxf(fminf(x2, wx2) - fmaxf(x1, wx1), 0.f);
          float ih = fmaxf(fminf(y2, wy2) - fmaxf(y1, wy1), 0.f);
          float ar = (x2 - x1) * (y2 - y1);
          if (iw * ih / ar > 0.5f) alive &= ~(1u << ss);  // winner self-clears
        }
      }
    }
    if (lane == 0) numKept = nk;
  }
  __syncthreads();

  // ---- output: kept rows then pad rows cand[j - n]; score from key bits ----
  const int n = numKept;
  if (tid < MAXB) {
    int j = tid;
    int r = (j < n) ? keptRank[j] : (j - n);
    ull pk = selPk[r];
    unsigned idx = ~(unsigned)pk;
    float sc = unfkey((unsigned)(pk >> 32));
    const float2* e2 = (const float2*)(xb + (size_t)idx * 6 + 2);
    float2 ra = e2[0], rb = e2[1];
    unsigned pp = (idx / 9u) % 60u;
    unsigned qq = idx / 540u;
    unsigned sr = idx % 9u;
    const float* ap = anch + (((pp * 40u + qq) * 9u + sr) * 4u);
    float ax = ap[0], ay = ap[1], aw = ap[2], ah = ap[3];
    float xc = ra.x * aw + ax;
    float yc = ra.y * ah + ay;
    float w = aw * expf(rb.x);
    float h = ah * expf(rb.y);
    float* o = out + s * (MAXB * 5) + j * 5;
    o[0] = xc; o[1] = yc; o[2] = w; o[3] = h; o[4] = sc;
  }
}

extern "C" void kernel_launch(void* const* d_in, const int* in_sizes, int n_in,
                              void* d_out, int out_size, void* d_ws, size_t ws_size,
                              hipStream_t stream) {
  const float* x = (const float*)d_in[0];
  const float* anch = (const float*)d_in[1];
  float* out = (float*)d_out;
  const int B = in_sizes[0] / (NELEM * 6);
  unsigned* ghist = (unsigned*)d_ws;                         // B*8*2048 u32
  unsigned* gkeys = ghist + (size_t)B * NCHUNK * 2048;       // B*21600 u32
  k1_scan<<<dim3(B * NCHUNK), dim3(NT), 0, stream>>>(x, gkeys, ghist);
  k2_main<<<dim3(B), dim3(NT), 0, stream>>>(x, anch, gkeys, ghist, out);
}